// Round 1
// baseline (349.025 us; speedup 1.0000x reference)
//
#include <hip/hip_runtime.h>

// CovarianceLayer: out = boxmean5x5( (center(x)-boxmean5x5(x)) * (center(y)-boxmean5x5(y)) )
// x,y: [16,1,1024,1024] fp32; out: [16,1,1016,1016] fp32.
//
// Structure: 64x64 output tile per block (256 threads).
//  P1: stage 72x72 x/y tiles into LDS (clamped loads; clamped region only feeds
//      out-of-range outputs, never stored).
//  P2: p[a][b] = (x[a+2][b+2] - S5x5(x)/25) * (y[a+2][b+2] - S5x5(y)/25) for 68x68,
//      via per-thread column sums (regs) + horizontal sliding window.
//  P3: colp[i][b] = vertical 5-sum of p (aliased over dead sx region).
//  P4: out[i][j] = horizontal 5-sum of colp / 25, sliding window per thread.

#define BATCH 16
#define H 1024
#define W 1024
#define OH 1016
#define OW 1016
#define TILE 64
#define XT 72          // TILE + 8 (x/y halo)
#define XTP 73         // padded pitch
#define PT 68          // TILE + 4 (p halo)
#define PTP 69         // padded pitch

__global__ __launch_bounds__(256) void cov_kernel(
    const float* __restrict__ x, const float* __restrict__ y,
    float* __restrict__ out)
{
    // 72*73*2 + 68*69 = 15204 floats = 60816 B
    __shared__ float smem[XT * XTP * 2 + PT * PTP];
    float* sx = smem;                  // [XT][XTP]
    float* sy = smem + XT * XTP;       // [XT][XTP]
    float* sp = smem + 2 * XT * XTP;   // [PT][PTP]
    float* colp = smem;                // [TILE][PTP], aliases sx (dead after P2)

    const int tid  = threadIdx.x;
    const int col0 = blockIdx.x * TILE;   // output col base
    const int row0 = blockIdx.y * TILE;   // output row base
    const int bz   = blockIdx.z;          // batch

    const float* __restrict__ xb = x + (size_t)bz * H * W;
    const float* __restrict__ yb = y + (size_t)bz * H * W;

    // ---- Phase 1: load 72x72 x/y tiles (edge-clamped) ----
    for (int idx = tid; idx < XT * XT; idx += 256) {
        int r = idx / XT, c = idx - r * XT;
        int gr = row0 + r; if (gr > H - 1) gr = H - 1;
        int gc = col0 + c; if (gc > W - 1) gc = W - 1;
        size_t g = (size_t)gr * W + gc;
        sx[r * XTP + c] = xb[g];
        sy[r * XTP + c] = yb[g];
    }
    __syncthreads();

    // ---- Phase 2: p tile 68x68. Units = 68 rows x 4 col-segments of 17 ----
    for (int unit = tid; unit < PT * 4; unit += 256) {
        int a   = unit >> 2;
        int seg = unit & 3;
        int b0  = seg * 17;              // 0,17,34,51; cols used b0..b0+20 <= 71

        float cx[21], cy[21];
        #pragma unroll
        for (int c = 0; c < 21; ++c) {
            int col = b0 + c;
            float sxs = 0.f, sys = 0.f;
            #pragma unroll
            for (int u = 0; u < 5; ++u) {
                sxs += sx[(a + u) * XTP + col];
                sys += sy[(a + u) * XTP + col];
            }
            cx[c] = sxs; cy[c] = sys;
        }
        float wx = cx[0] + cx[1] + cx[2] + cx[3] + cx[4];
        float wy = cy[0] + cy[1] + cy[2] + cy[3] + cy[4];
        #pragma unroll
        for (int j = 0; j < 17; ++j) {
            int b = b0 + j;
            float ctx = sx[(a + 2) * XTP + (b + 2)];
            float cty = sy[(a + 2) * XTP + (b + 2)];
            float p = (ctx - wx * (1.f / 25.f)) * (cty - wy * (1.f / 25.f));
            sp[a * PTP + b] = p;
            if (j < 16) { wx += cx[j + 5] - cx[j]; wy += cy[j + 5] - cy[j]; }
        }
    }
    __syncthreads();

    // ---- Phase 3: colp[i][b] = sum_{u=0..4} p[i+u][b], i<64, b<68 ----
    for (int idx = tid; idx < TILE * PT; idx += 256) {
        int i = idx / PT, b = idx - i * PT;
        float s = 0.f;
        #pragma unroll
        for (int u = 0; u < 5; ++u) s += sp[(i + u) * PTP + b];
        colp[i * PTP + b] = s;
    }
    __syncthreads();

    // ---- Phase 4: out row i, 4 segments of 16 cols; horizontal 5-sum / 25 ----
    {
        int i   = tid >> 2;
        int seg = tid & 3;
        int b0  = seg * 16;              // cols used b0..b0+19 <= 67

        float c[20];
        #pragma unroll
        for (int k = 0; k < 20; ++k) c[k] = colp[i * PTP + b0 + k];
        float w = c[0] + c[1] + c[2] + c[3] + c[4];

        int gr = row0 + i;
        if (gr < OH) {
            float* orow = out + (size_t)bz * OH * OW + (size_t)gr * OW;
            #pragma unroll
            for (int j = 0; j < 16; ++j) {
                int gc = col0 + b0 + j;
                if (gc < OW) orow[gc] = w * (1.f / 25.f);
                if (j < 15) { w += c[j + 5] - c[j]; }
            }
        }
    }
}

extern "C" void kernel_launch(void* const* d_in, const int* in_sizes, int n_in,
                              void* d_out, int out_size, void* d_ws, size_t ws_size,
                              hipStream_t stream) {
    const float* x = (const float*)d_in[0];
    const float* y = (const float*)d_in[1];
    // d_in[2]/d_in[3] are the constant conv masks (1/25 box, center impulse) — baked in.
    float* out = (float*)d_out;

    dim3 grid(16, 16, BATCH);   // 16x16 tiles of 64x64 cover 1024>=1016
    dim3 block(256);
    hipLaunchKernelGGL(cov_kernel, grid, block, 0, stream, x, y, out);
}

// Round 2
// 186.097 us; speedup vs baseline: 1.8755x; 1.8755x over previous
//
#include <hip/hip_runtime.h>

// CovarianceLayer: out = boxmean5x5( (center(x)-boxmean5x5(x)) * (center(y)-boxmean5x5(y)) )
// x,y: [16,1,1024,1024] fp32; out: [16,1,1016,1016] fp32.
//
// Register-resident vertical-scan formulation (no LDS, no __syncthreads):
//  - each WAVE owns a 256-input-column strip (lane k -> float4 at col base+4k),
//    slides down a 32-output-row chunk (40 input rows incl. 8 priming rows).
//  - vertical 5-row box sums vx,vy,vp held as running sums + 5-deep float4 ring
//    buffers (static indices via 5x inner unroll).
//  - horizontal 5-sums via __shfl_up/__shfl_down of neighbor-lane edge elements
//    (sliding-window within the lane's 4 columns).
//  - p = (center_x - vxh/25)*(center_y - vyh/25) at center-indexed rows;
//    second box filter identical in structure; out row i emitted after loading
//    input row i+8.
// Valid outputs per 256-col wave strip: 248 cols (lanes 1..62). 5 strips cover
// 1016. Edge lanes' shfl out-of-range returns own value (finite) -> garbage
// only ever flows into masked-off outputs; sliding-window cancellation is
// ~ulp-level fp noise.

#define W 1024
#define H 1024
#define OW 1016
#define OH 1016
#define NBATCH 16
#define NSTRIP 5
#define NCHUNK 32
#define RCHUNK 32
#define NSTEP (RCHUNK + 8)    // 40 input rows per job
#define STRIP_OUT 248

__device__ __forceinline__ float shfl_up1(float v) { return __shfl_up(v, 1, 64); }
__device__ __forceinline__ float shfl_dn1(float v) { return __shfl_down(v, 1, 64); }

__global__ __launch_bounds__(256) void cov_kernel(
    const float* __restrict__ x, const float* __restrict__ y,
    float* __restrict__ out)
{
    const int wid  = (blockIdx.x << 2) + (threadIdx.x >> 6);
    const int lane = threadIdx.x & 63;

    // job decode: chunk fastest (adjacent waves share row halo in L2)
    const int chunk = wid & (NCHUNK - 1);
    const int rest  = wid >> 5;
    const int strip = rest % NSTRIP;
    const int batch = rest / NSTRIP;

    const int o0   = chunk * RCHUNK;      // first output row of this job
    const int base = strip * STRIP_OUT;   // first input col of this strip

    int col4 = base + (lane << 2);
    if (col4 > W - 4) col4 = W - 4;       // clamp (strip 4 tail lanes; masked below)

    const float* __restrict__ xb = x + (size_t)batch * H * W;
    const float* __restrict__ yb = y + (size_t)batch * H * W;
    float* __restrict__ ob = out + (size_t)batch * OH * OW;

    const int j4 = base + ((lane - 1) << 2);   // first output col this lane stores
    const bool lane_ok = (lane >= 1) && (lane <= 62) && (j4 <= OW - 4);

    constexpr float inv25 = 1.0f / 25.0f;

    float4 xr[5], yr[5], pr[5];
    float4 vx = make_float4(0.f, 0.f, 0.f, 0.f);
    float4 vy = vx, vp = vx;
    #pragma unroll
    for (int u = 0; u < 5; ++u) { xr[u] = vx; yr[u] = vx; pr[u] = vx; }

    for (int t = 0; t < NSTEP / 5; ++t) {
        #pragma unroll
        for (int u = 0; u < 5; ++u) {
            const int s = t * 5 + u;
            int r = o0 + s; if (r > H - 1) r = H - 1;
            const int off = r * W + col4;
            const float4 xn = *(const float4*)(xb + off);
            const float4 yn = *(const float4*)(yb + off);

            // vertical running 5-sums (rows s-4..s), ring replaces row s-5
            vx.x += xn.x - xr[u].x; vx.y += xn.y - xr[u].y;
            vx.z += xn.z - xr[u].z; vx.w += xn.w - xr[u].w;
            vy.x += yn.x - yr[u].x; vy.y += yn.y - yr[u].y;
            vy.z += yn.z - yr[u].z; vy.w += yn.w - yr[u].w;
            xr[u] = xn; yr[u] = yn;

            // horizontal 5-sums at this lane's 4 cols (neighbors via shfl)
            const float vxl0 = shfl_up1(vx.z), vxl1 = shfl_up1(vx.w);
            const float vxr0 = shfl_dn1(vx.x), vxr1 = shfl_dn1(vx.y);
            const float vyl0 = shfl_up1(vy.z), vyl1 = shfl_up1(vy.w);
            const float vyr0 = shfl_dn1(vy.x), vyr1 = shfl_dn1(vy.y);

            const float hx0 = vxl0 + vxl1 + vx.x + vx.y + vx.z;
            const float hx1 = hx0 - vxl0 + vx.w;
            const float hx2 = hx1 - vxl1 + vxr0;
            const float hx3 = hx2 - vx.x + vxr1;
            const float hy0 = vyl0 + vyl1 + vy.x + vy.y + vy.z;
            const float hy1 = hy0 - vyl0 + vy.w;
            const float hy2 = hy1 - vyl1 + vyr0;
            const float hy3 = hy2 - vy.x + vyr1;

            // centers: row r-2 = ring slot (u+3)%5
            const float4 cx4 = xr[(u + 3) % 5];
            const float4 cy4 = yr[(u + 3) % 5];

            float4 p;
            p.x = (cx4.x - hx0 * inv25) * (cy4.x - hy0 * inv25);
            p.y = (cx4.y - hx1 * inv25) * (cy4.y - hy1 * inv25);
            p.z = (cx4.z - hx2 * inv25) * (cy4.z - hy2 * inv25);
            p.w = (cx4.w - hx3 * inv25) * (cy4.w - hy3 * inv25);

            // vertical running 5-sum of p
            vp.x += p.x - pr[u].x; vp.y += p.y - pr[u].y;
            vp.z += p.z - pr[u].z; vp.w += p.w - pr[u].w;
            pr[u] = p;

            const int i = o0 + s - 8;          // output row
            if (s >= 8 && i < OH) {            // wave-uniform condition
                const float vpl0 = shfl_up1(vp.z), vpl1 = shfl_up1(vp.w);
                const float vpr0 = shfl_dn1(vp.x), vpr1 = shfl_dn1(vp.y);
                const float h0 = vpl0 + vpl1 + vp.x + vp.y + vp.z;
                const float h1 = h0 - vpl0 + vp.w;
                const float h2 = h1 - vpl1 + vpr0;
                const float h3 = h2 - vp.x + vpr1;
                if (lane_ok) {
                    float4 o4 = make_float4(h0 * inv25, h1 * inv25,
                                            h2 * inv25, h3 * inv25);
                    *(float4*)(ob + (size_t)i * OW + j4) = o4;
                }
            }
        }
    }
}

extern "C" void kernel_launch(void* const* d_in, const int* in_sizes, int n_in,
                              void* d_out, int out_size, void* d_ws, size_t ws_size,
                              hipStream_t stream) {
    const float* x = (const float*)d_in[0];
    const float* y = (const float*)d_in[1];
    // d_in[2]/d_in[3]: constant conv masks (1/25 box, center impulse) — baked in.
    float* out = (float*)d_out;

    // 16 batch x 5 strips x 32 row-chunks = 2560 wave-jobs = 640 blocks x 4 waves
    dim3 grid(NBATCH * NSTRIP * NCHUNK / 4);
    dim3 block(256);
    hipLaunchKernelGGL(cov_kernel, grid, block, 0, stream, x, y, out);
}